// Round 14
// baseline (115.882 us; speedup 1.0000x reference)
//
#include <hip/hip_runtime.h>

#define BATCH 131072
#define NS    300
#define H     100
#define BLK   256
#define EPB   64
#define NBLK  (BATCH / EPB)        /* 2048 blocks for the MLP kernel */
#define H2STR 112
#define LOOFF 14336

/* workspace layout (bytes) */
#define WS_P0   0
#define WS_P1   2097152
#define WS_P2   4194304
#define WS_WSB  6291456            /* 57344 B  bf16 W2 frags */
#define WS_HDT  6348800            /*  5376 B  head table */
#define WS_B2P  6354176            /*   448 B  padded b2 */

typedef __attribute__((ext_vector_type(8))) short bf16x8;
typedef __attribute__((ext_vector_type(4))) float f32x4;

__device__ __forceinline__ unsigned short f2bf(float f) {
    unsigned int u = __float_as_uint(f);
    return (unsigned short)((u + 0x7fffu + ((u >> 16) & 1u)) >> 16);
}
__device__ __forceinline__ float bf2f(unsigned short h) {
    return __uint_as_float(((unsigned int)h) << 16);
}

/* B-frags of W2^T, split-bf16, zero-padded 128x112 (verbatim R11/R13, HW-verified). */
__global__ void prep_w2(const float* __restrict__ W2, unsigned short* __restrict__ wsb) {
    const int fi   = blockIdx.x * 4 + (threadIdx.x >> 6);
    const int lane = threadIdx.x & 63;
    const int s = fi / 7, t = fi % 7;
    const int n  = t * 16 + (lane & 15);
    const int k0 = s * 32 + ((lane >> 4) << 3);
    unsigned short* hi = wsb + ((size_t)fi * 64 + lane) * 8;
#pragma unroll
    for (int i = 0; i < 8; ++i) {
        const int k = k0 + i;
        const float v = (k < H && n < H) ? W2[n * H + k] : 0.f;
        const unsigned short h = f2bf(v);
        hi[i]         = h;
        hi[LOOFF + i] = f2bf(v - bf2f(h));
    }
}

__global__ void prep_small(const float* __restrict__ Ww0, const float* __restrict__ Wwp,
                           const float* __restrict__ Wg,  const float* __restrict__ b2,
                           float* __restrict__ hdt, float* __restrict__ b2p) {
    const int i = blockIdx.x * 256 + threadIdx.x;
    if (i < 12 * 112) {
        const int c = i / 112, j = i % 112;
        const float* src = (c < 4) ? Ww0 : (c < 8) ? Wwp : Wg;
        hdt[i] = (j < H) ? src[(c & 3) * H + j] : 0.f;
    }
    if (i < 112) b2p[i] = (i < H) ? b2[i] : 0.f;
}

/* ---------------- kernel A: MLP -> params (R13 math, barrier-free) ---------------- */
__global__ __launch_bounds__(BLK)
void lorentz_mlp(const float* __restrict__ G,   const float* __restrict__ W1,
                 const float* __restrict__ b1,  const unsigned short* __restrict__ wsb,
                 const float* __restrict__ hdt, const float* __restrict__ b2p,
                 float* __restrict__ p0f, float* __restrict__ p1f, float* __restrict__ p2f)
{
    __shared__ __align__(16) float h2buf[4][16][H2STR];  /* per-wave slabs, no barriers */

    const int tid  = threadIdx.x;
    const int w    = tid >> 6, lane = tid & 63, ln = lane & 15, gr = lane >> 4;
    const int e0w  = blockIdx.x * EPB + w * 16;

    const float4* gp = (const float4*)(G + (size_t)(e0w + ln) * 8);
    const float4 gA = gp[0], gB = gp[1];

    f32x4 acc[7];
#pragma unroll
    for (int t = 0; t < 7; ++t) acc[t] = (f32x4){0.f, 0.f, 0.f, 0.f};

    const bf16x8* Bf = (const bf16x8*)wsb;

#pragma unroll
    for (int s = 0; s < 4; ++s) {
        bf16x8 ahi, alo;
#pragma unroll
        for (int i = 0; i < 8; ++i) {
            const int k  = s * 32 + gr * 8 + i;
            const int kc = (k < H) ? k : (H - 1);
            const float4 ra = ((const float4*)(W1 + kc * 8))[0];
            const float4 rb = ((const float4*)(W1 + kc * 8))[1];
            float s0 = fmaf(gA.x, ra.x, b1[kc]);
            float s1 = gA.y * ra.y;
            s0 = fmaf(gA.z, ra.z, s0);  s1 = fmaf(gA.w, ra.w, s1);
            s0 = fmaf(gB.x, rb.x, s0);  s1 = fmaf(gB.y, rb.y, s1);
            s0 = fmaf(gB.z, rb.z, s0);  s1 = fmaf(gB.w, rb.w, s1);
            const float h = fmaxf(s0 + s1, 0.f);
            const unsigned short hh = f2bf(h);
            ahi[i] = (short)hh;
            alo[i] = (short)f2bf(h - bf2f(hh));
        }
#pragma unroll
        for (int t = 0; t < 7; ++t) {
            const bf16x8 bh = Bf[(s * 7 + t) * 64 + lane];
            const bf16x8 bl = Bf[1792 + (s * 7 + t) * 64 + lane];
            acc[t] = __builtin_amdgcn_mfma_f32_16x16x32_bf16(ahi, bh, acc[t], 0, 0, 0);
            acc[t] = __builtin_amdgcn_mfma_f32_16x16x32_bf16(ahi, bl, acc[t], 0, 0, 0);
            acc[t] = __builtin_amdgcn_mfma_f32_16x16x32_bf16(alo, bh, acc[t], 0, 0, 0);
        }
    }

    /* h2 -> own wave's slab (C/D layout verified m89); same-wave RAW via lgkmcnt */
#pragma unroll
    for (int t = 0; t < 7; ++t) {
        const float b2v = b2p[t * 16 + ln];
#pragma unroll
        for (int r = 0; r < 4; ++r)
            h2buf[w][gr * 4 + r][t * 16 + ln] = fmaxf(acc[t][r] + b2v, 0.f);
    }

    /* heads: lane (row=lane>>2, q=lane&3); writes contiguous 64 floats per wave */
    {
        const int row = lane >> 2, q = lane & 3;
        const float4* h4 = (const float4*)&h2buf[w][row][0];
        const float4* d0 = (const float4*)(hdt + q * 112);
        const float4* d1 = (const float4*)(hdt + (4 + q) * 112);
        const float4* d2 = (const float4*)(hdt + (8 + q) * 112);
        float s0 = 0.f, s1 = 0.f, s2 = 0.f;
#pragma unroll
        for (int k4 = 0; k4 < 28; ++k4) {
            const float4 hv = h4[k4];
            const float4 a = d0[k4], b = d1[k4], c = d2[k4];
            s0 = fmaf(hv.x, a.x, s0); s1 = fmaf(hv.x, b.x, s1); s2 = fmaf(hv.x, c.x, s2);
            s0 = fmaf(hv.y, a.y, s0); s1 = fmaf(hv.y, b.y, s1); s2 = fmaf(hv.y, c.y, s2);
            s0 = fmaf(hv.z, a.z, s0); s1 = fmaf(hv.z, b.z, s1); s2 = fmaf(hv.z, c.z, s2);
            s0 = fmaf(hv.w, a.w, s0); s1 = fmaf(hv.w, b.w, s1); s2 = fmaf(hv.w, c.w, s2);
        }
        const float w0 = fmaxf(s0, 0.f), wp = fmaxf(s1, 0.f), gg = fmaxf(s2, 0.f);
        const int gi = e0w * 4 + lane;       /* (e0w+row)*4+q == e0w*4+lane: coalesced */
        p0f[gi] = w0 * w0;
        p1f[gi] = gg * gg;
        p2f[gi] = wp * wp * gg;
    }
}

/* ---------------- kernel B: pure streaming spectrum (fillBuffer-shaped) ---------------- */
#define SGRID 2048
#define NQTOT (BATCH * NS / 4)     /* 9,830,400 float4 outputs */

__global__ __launch_bounds__(BLK)
void lorentz_spec(const float4* __restrict__ p0g, const float4* __restrict__ p1g,
                  const float4* __restrict__ p2g, float4* __restrict__ out4)
{
    int idx = blockIdx.x * BLK + threadIdx.x;
    const int stride = SGRID * BLK;            /* 524288 */
#pragma unroll 1
    for (; idx < NQTOT; idx += stride) {       /* 18-19 iterations */
        const int e  = idx / 75;               /* magic-mul divide */
        const int k4 = idx - e * 75;
        const float4 P0 = p0g[e], P1 = p1g[e], P2 = p2g[e];   /* broadcast, L2-hot */
        const float kb = (float)(k4 << 2);
        float4 r; float* rp = (float*)&r;
#pragma unroll
        for (int i = 0; i < 4; ++i) {
            const float w_  = 0.5f + (kb + (float)i) * 0.015f;
            const float wsq = w_ * w_;
            const float t0 = P0.x - wsq, t1 = P0.y - wsq,
                        t2 = P0.z - wsq, t3 = P0.w - wsq;
            const float d0 = fmaf(t0, t0, wsq * P1.x);
            const float d1 = fmaf(t1, t1, wsq * P1.y);
            const float d2 = fmaf(t2, t2, wsq * P1.z);
            const float d3 = fmaf(t3, t3, wsq * P1.w);
            const float d01 = d0 * d1, d23 = d2 * d3;
            const float D   = d01 * d23;
            const float n01 = fmaf(P2.y, d0, P2.x * d1);
            const float n23 = fmaf(P2.w, d2, P2.z * d3);
            const float N   = fmaf(n01, d23, n23 * d01);
            rp[i] = w_ * (N * __builtin_amdgcn_rcpf(D));
        }
        out4[idx] = r;
    }
}

extern "C" void kernel_launch(void* const* d_in, const int* in_sizes, int n_in,
                              void* d_out, int out_size, void* d_ws, size_t ws_size,
                              hipStream_t stream) {
    const float* G   = (const float*)d_in[0];
    const float* W1  = (const float*)d_in[1];
    const float* b1  = (const float*)d_in[2];
    const float* W2  = (const float*)d_in[3];
    const float* b2  = (const float*)d_in[4];
    const float* Ww0 = (const float*)d_in[5];
    const float* Wwp = (const float*)d_in[6];
    const float* Wg  = (const float*)d_in[7];
    float* out = (float*)d_out;

    char* ws = (char*)d_ws;
    float*          p0f = (float*)(ws + WS_P0);
    float*          p1f = (float*)(ws + WS_P1);
    float*          p2f = (float*)(ws + WS_P2);
    unsigned short* wsb = (unsigned short*)(ws + WS_WSB);
    float*          hdt = (float*)(ws + WS_HDT);
    float*          b2p = (float*)(ws + WS_B2P);

    prep_w2<<<7, 256, 0, stream>>>(W2, wsb);
    prep_small<<<6, 256, 0, stream>>>(Ww0, Wwp, Wg, b2, hdt, b2p);
    lorentz_mlp<<<NBLK, BLK, 0, stream>>>(G, W1, b1, wsb, hdt, b2p, p0f, p1f, p2f);
    lorentz_spec<<<SGRID, BLK, 0, stream>>>((const float4*)p0f, (const float4*)p1f,
                                            (const float4*)p2f, (float4*)out);
}